// Round 1
// baseline (146.150 us; speedup 1.0000x reference)
//
#include <hip/hip_runtime.h>
#include <stdint.h>

#define HIDDEN 768
#define META 25
#define EDC 300
#define BB 2
#define NMENT 2000
#define NPAIRS 40000
#define M_ROWS (BB * NMENT)       // 4000
#define M_PAD 4032                // 63 * 64
#define N_OUT 1536
#define TOTAL_PAIRS (BB * NPAIRS) // 80000

typedef __bf16 bf16x8 __attribute__((ext_vector_type(8)));
typedef float f32x4 __attribute__((ext_vector_type(4)));

static __device__ __forceinline__ float bf2f(unsigned short u) {
    union { unsigned int u; float f; } v; v.u = ((unsigned int)u) << 16; return v.f;
}
static __device__ __forceinline__ unsigned short f2bf(float f) {
    union { float f; unsigned int u; } v; v.f = f;
    unsigned int u = v.u;
    unsigned int r = (u + 0x7FFFu + ((u >> 16) & 1u)) >> 16;   // RNE
    return (unsigned short)r;
}

// ---- fp32 mentions -> bf16, padded to 4032 rows (zero fill) ----
__global__ void k_convM(const float* __restrict__ M, unsigned short* __restrict__ Mb) {
    int idx = (blockIdx.x * 256 + threadIdx.x) * 4;
    if (idx >= M_PAD * HIDDEN) return;
    int row = idx / HIDDEN;
    ushort4 o;
    if (row < M_ROWS) {
        const float4 v = *(const float4*)(M + idx);
        o.x = f2bf(v.x); o.y = f2bf(v.y); o.z = f2bf(v.z); o.w = f2bf(v.w);
    } else {
        o.x = 0; o.y = 0; o.z = 0; o.w = 0;
    }
    *(ushort4*)(Mb + idx) = o;
}

// ---- W1 combined view -> Wt[n][k] bf16, transposed via LDS tile ----
// Bcomb[k][n] = (n<768) ? W1[k][n] : W1[768+k][n-768],  k in [0,768), n in [0,1536)
__global__ void k_convW(const float* __restrict__ W1, unsigned short* __restrict__ Wt) {
    __shared__ float tile[32][68];
    int nt = blockIdx.x % 24, kt = blockIdx.x / 24;
    int n0 = nt * 64, k0 = kt * 32;
    int t = threadIdx.x;
    int tk = t >> 4, tn = (t & 15) * 4;
    int srcRowOff = (n0 < HIDDEN) ? 0 : HIDDEN;
    int srcColBase = (n0 < HIDDEN) ? n0 : (n0 - HIDDEN);
    {
        const float4 v0 = *(const float4*)(W1 + (size_t)(k0 + tk + srcRowOff) * HIDDEN + srcColBase + tn);
        tile[tk][tn] = v0.x; tile[tk][tn + 1] = v0.y; tile[tk][tn + 2] = v0.z; tile[tk][tn + 3] = v0.w;
        const float4 v1 = *(const float4*)(W1 + (size_t)(k0 + tk + 16 + srcRowOff) * HIDDEN + srcColBase + tn);
        tile[tk + 16][tn] = v1.x; tile[tk + 16][tn + 1] = v1.y; tile[tk + 16][tn + 2] = v1.z; tile[tk + 16][tn + 3] = v1.w;
    }
    __syncthreads();
    int wn = t >> 2, wk = (t & 3) * 8;
    unsigned int p0 = (unsigned int)f2bf(tile[wk + 0][wn]) | ((unsigned int)f2bf(tile[wk + 1][wn]) << 16);
    unsigned int p1 = (unsigned int)f2bf(tile[wk + 2][wn]) | ((unsigned int)f2bf(tile[wk + 3][wn]) << 16);
    unsigned int p2 = (unsigned int)f2bf(tile[wk + 4][wn]) | ((unsigned int)f2bf(tile[wk + 5][wn]) << 16);
    unsigned int p3 = (unsigned int)f2bf(tile[wk + 6][wn]) | ((unsigned int)f2bf(tile[wk + 7][wn]) << 16);
    uint4 pk; pk.x = p0; pk.y = p1; pk.z = p2; pk.w = p3;
    *(uint4*)(Wt + (size_t)(n0 + wn) * HIDDEN + k0 + wk) = pk;
}

// ---- E''[e][n] = ed_table[e] @ W1[1536:1561] + b1  (fp32) ----
__global__ void k_prep(const float* __restrict__ ed_table, const float* __restrict__ W1,
                       const float* __restrict__ b1, float* __restrict__ Epp) {
    int id = blockIdx.x * 256 + threadIdx.x;
    if (id >= EDC * HIDDEN) return;
    int e = id / HIDDEN, n = id - e * HIDDEN;
    float acc = b1[n];
#pragma unroll
    for (int k = 0; k < META; k++)
        acc += ed_table[e * META + k] * W1[(size_t)(2 * HIDDEN + k) * HIDDEN + n];
    Epp[id] = acc;
}

// ---- AW[4032][1536] = Mb @ Wt^T  (bf16 in, fp32 acc, bf16 out) ----
__global__ __launch_bounds__(256) void k_gemm(const unsigned short* __restrict__ Mb,
                                              const unsigned short* __restrict__ Wt,
                                              unsigned short* __restrict__ AW) {
    __shared__ unsigned short As[64][40];   // [m][k], pad 32->40 (2-way bank alias = free)
    __shared__ unsigned short Bs[64][40];   // [n][k]
    const int m0 = blockIdx.x * 64;
    const int n0 = blockIdx.y * 64;
    const int t = threadIdx.x;
    const int srow = t >> 2, skc = (t & 3) * 8;
    const int w = t >> 6, lane = t & 63;
    const int wm = (w & 1) * 32, wn = (w >> 1) * 32;
    const int q = lane >> 4, r = lane & 15;
    f32x4 acc00 = {0.f, 0.f, 0.f, 0.f};
    f32x4 acc01 = {0.f, 0.f, 0.f, 0.f};
    f32x4 acc10 = {0.f, 0.f, 0.f, 0.f};
    f32x4 acc11 = {0.f, 0.f, 0.f, 0.f};
    for (int k0 = 0; k0 < HIDDEN; k0 += 32) {
        *(uint4*)&As[srow][skc] = *(const uint4*)(Mb + (size_t)(m0 + srow) * HIDDEN + k0 + skc);
        *(uint4*)&Bs[srow][skc] = *(const uint4*)(Wt + (size_t)(n0 + srow) * HIDDEN + k0 + skc);
        __syncthreads();
        bf16x8 a0 = *(const bf16x8*)&As[wm + r][q * 8];
        bf16x8 a1 = *(const bf16x8*)&As[wm + 16 + r][q * 8];
        bf16x8 b0 = *(const bf16x8*)&Bs[wn + r][q * 8];
        bf16x8 b1 = *(const bf16x8*)&Bs[wn + 16 + r][q * 8];
        acc00 = __builtin_amdgcn_mfma_f32_16x16x32_bf16(a0, b0, acc00, 0, 0, 0);
        acc01 = __builtin_amdgcn_mfma_f32_16x16x32_bf16(a0, b1, acc01, 0, 0, 0);
        acc10 = __builtin_amdgcn_mfma_f32_16x16x32_bf16(a1, b0, acc10, 0, 0, 0);
        acc11 = __builtin_amdgcn_mfma_f32_16x16x32_bf16(a1, b1, acc11, 0, 0, 0);
        __syncthreads();
    }
    // C/D layout: col = lane&15, row = (lane>>4)*4 + reg   [verified mapping]
    const int col0 = n0 + wn + (lane & 15);
    const int row0 = m0 + wm + (lane >> 4) * 4;
#pragma unroll
    for (int reg = 0; reg < 4; reg++) {
        AW[(size_t)(row0 + reg) * N_OUT + col0]           = f2bf(acc00[reg]);
        AW[(size_t)(row0 + reg) * N_OUT + col0 + 16]      = f2bf(acc01[reg]);
        AW[(size_t)(row0 + 16 + reg) * N_OUT + col0]      = f2bf(acc10[reg]);
        AW[(size_t)(row0 + 16 + reg) * N_OUT + col0 + 16] = f2bf(acc11[reg]);
    }
}

// ---- pair phase: 1 wave per pair ----
__global__ __launch_bounds__(256) void k_pair(const unsigned short* __restrict__ AW,
                                              const float* __restrict__ Epp,
                                              const float* __restrict__ W2,
                                              const float* __restrict__ b2,
                                              const int* __restrict__ pairs,
                                              const int* __restrict__ eds,
                                              float* __restrict__ out) {
    int p = blockIdx.x * 4 + (threadIdx.x >> 6);
    int lane = threadIdx.x & 63;
    int b = (p >= NPAIRS) ? 1 : 0;
    int i0 = pairs[p * 2 + 0];
    int i1 = pairs[p * 2 + 1];
    int ed = eds[p];
    const unsigned short* a1p = AW + (size_t)(b * NMENT + i0) * N_OUT;
    const unsigned short* a2p = AW + (size_t)(b * NMENT + i1) * N_OUT + HIDDEN;
    const float* ep = Epp + (size_t)ed * HIDDEN;
    float acc = 0.f;
#pragma unroll
    for (int j = 0; j < 3; j++) {
        int n = j * 256 + lane * 4;
        ushort4 u1 = *(const ushort4*)(a1p + n);
        ushort4 u2 = *(const ushort4*)(a2p + n);
        float4 e = *(const float4*)(ep + n);
        float4 wv = *(const float4*)(W2 + n);
        float h;
        h = bf2f(u1.x) + bf2f(u2.x) + e.x; h = fmaxf(h, 0.f); acc += h * wv.x;
        h = bf2f(u1.y) + bf2f(u2.y) + e.y; h = fmaxf(h, 0.f); acc += h * wv.y;
        h = bf2f(u1.z) + bf2f(u2.z) + e.z; h = fmaxf(h, 0.f); acc += h * wv.z;
        h = bf2f(u1.w) + bf2f(u2.w) + e.w; h = fmaxf(h, 0.f); acc += h * wv.w;
    }
#pragma unroll
    for (int off = 32; off > 0; off >>= 1) acc += __shfl_xor(acc, off, 64);
    if (lane == 0) out[p] = acc + b2[0];
}

extern "C" void kernel_launch(void* const* d_in, const int* in_sizes, int n_in,
                              void* d_out, int out_size, void* d_ws, size_t ws_size,
                              hipStream_t stream) {
    const float* mention  = (const float*)d_in[0];
    const int*   pairs    = (const int*)d_in[1];
    const int*   eds      = (const int*)d_in[2];
    const float* ed_table = (const float*)d_in[3];
    const float* W1       = (const float*)d_in[4];
    const float* b1       = (const float*)d_in[5];
    const float* W2       = (const float*)d_in[6];
    const float* b2       = (const float*)d_in[7];
    float* out = (float*)d_out;

    // workspace layout (total ~21.9 MB)
    char* ws = (char*)d_ws;
    unsigned short* Mb  = (unsigned short*)(ws);                                   // 4032*768*2  = 6,193,152
    unsigned short* Wt  = (unsigned short*)(ws + 6193152);                         // 1536*768*2  = 2,359,296
    unsigned short* AW  = (unsigned short*)(ws + 6193152 + 2359296);               // 4032*1536*2 = 12,386,304
    float*          Epp = (float*)(ws + 6193152 + 2359296 + 12386304);             // 300*768*4   = 921,600

    k_convM<<<dim3((M_PAD * HIDDEN / 4 + 255) / 256), dim3(256), 0, stream>>>(mention, Mb);
    k_convW<<<dim3(24 * 24), dim3(256), 0, stream>>>(W1, Wt);
    k_prep<<<dim3((EDC * HIDDEN + 255) / 256), dim3(256), 0, stream>>>(ed_table, W1, b1, Epp);
    k_gemm<<<dim3(M_PAD / 64, N_OUT / 64), dim3(256), 0, stream>>>(Mb, Wt, AW);
    k_pair<<<dim3(TOTAL_PAIRS / 4), dim3(256), 0, stream>>>(AW, Epp, W2, b2, pairs, eds, out);
}

// Round 2
// 134.611 us; speedup vs baseline: 1.0857x; 1.0857x over previous
//
#include <hip/hip_runtime.h>
#include <stdint.h>

#define HIDDEN 768
#define META 25
#define EDC 300
#define BB 2
#define NMENT 2000
#define NPAIRS 40000
#define M_ROWS (BB * NMENT)       // 4000
#define M_PAD 4096                // 32 * 128
#define N_OUT 1536
#define TOTAL_PAIRS (BB * NPAIRS) // 80000
#define BK 32

typedef __bf16 bf16x8 __attribute__((ext_vector_type(8)));
typedef float f32x4 __attribute__((ext_vector_type(4)));

static __device__ __forceinline__ float bf2f(unsigned short u) {
    union { unsigned int u; float f; } v; v.u = ((unsigned int)u) << 16; return v.f;
}
static __device__ __forceinline__ unsigned short f2bf(float f) {
    union { float f; unsigned int u; } v; v.f = f;
    unsigned int u = v.u;
    unsigned int r = (u + 0x7FFFu + ((u >> 16) & 1u)) >> 16;   // RNE
    return (unsigned short)r;
}

#define GLOAD_LDS16(g, l)                                                            \
    __builtin_amdgcn_global_load_lds((const __attribute__((address_space(1))) void*)(g), \
                                     (__attribute__((address_space(3))) void*)(l), 16, 0, 0)

// ---- fused prep: convM (3072 blocks) | convW (576 blocks) | ed prep (900 blocks) ----
#define NB_CONVM 3072              // (4096*768/4)/256
#define NB_CONVW 576               // 24*24
#define NB_PREP  900               // 300*768/256

__global__ __launch_bounds__(256) void k_prep_all(
        const float* __restrict__ M, unsigned short* __restrict__ Mb,
        const float* __restrict__ W1, unsigned short* __restrict__ Wt,
        const float* __restrict__ ed_table, const float* __restrict__ b1,
        unsigned short* __restrict__ Epp) {
    const int blk = blockIdx.x;
    const int t = threadIdx.x;
    if (blk < NB_CONVM) {
        // fp32 mentions -> bf16, padded to 4096 rows (zero fill)
        int idx = (blk * 256 + t) * 4;
        int row = idx / HIDDEN;
        ushort4 o;
        if (row < M_ROWS) {
            const float4 v = *(const float4*)(M + idx);
            o.x = f2bf(v.x); o.y = f2bf(v.y); o.z = f2bf(v.z); o.w = f2bf(v.w);
        } else {
            o.x = 0; o.y = 0; o.z = 0; o.w = 0;
        }
        *(ushort4*)(Mb + idx) = o;
    } else if (blk < NB_CONVM + NB_CONVW) {
        // W1 combined view -> Wt[n][k] bf16 (transpose via LDS tile)
        __shared__ float tile[32][68];
        int id = blk - NB_CONVM;
        int nt = id % 24, kt = id / 24;
        int n0 = nt * 64, k0 = kt * 32;
        int tk = t >> 4, tn = (t & 15) * 4;
        int srcRowOff = (n0 < HIDDEN) ? 0 : HIDDEN;
        int srcColBase = (n0 < HIDDEN) ? n0 : (n0 - HIDDEN);
        {
            const float4 v0 = *(const float4*)(W1 + (size_t)(k0 + tk + srcRowOff) * HIDDEN + srcColBase + tn);
            tile[tk][tn] = v0.x; tile[tk][tn + 1] = v0.y; tile[tk][tn + 2] = v0.z; tile[tk][tn + 3] = v0.w;
            const float4 v1 = *(const float4*)(W1 + (size_t)(k0 + tk + 16 + srcRowOff) * HIDDEN + srcColBase + tn);
            tile[tk + 16][tn] = v1.x; tile[tk + 16][tn + 1] = v1.y; tile[tk + 16][tn + 2] = v1.z; tile[tk + 16][tn + 3] = v1.w;
        }
        __syncthreads();
        int wn = t >> 2, wk = (t & 3) * 8;
        unsigned int p0 = (unsigned int)f2bf(tile[wk + 0][wn]) | ((unsigned int)f2bf(tile[wk + 1][wn]) << 16);
        unsigned int p1 = (unsigned int)f2bf(tile[wk + 2][wn]) | ((unsigned int)f2bf(tile[wk + 3][wn]) << 16);
        unsigned int p2 = (unsigned int)f2bf(tile[wk + 4][wn]) | ((unsigned int)f2bf(tile[wk + 5][wn]) << 16);
        unsigned int p3 = (unsigned int)f2bf(tile[wk + 6][wn]) | ((unsigned int)f2bf(tile[wk + 7][wn]) << 16);
        uint4 pk; pk.x = p0; pk.y = p1; pk.z = p2; pk.w = p3;
        *(uint4*)(Wt + (size_t)(n0 + wn) * HIDDEN + k0 + wk) = pk;
    } else {
        // E''[e][n] = ed_table[e] @ W1[1536:1561] + b1  -> bf16
        int id = (blk - NB_CONVM - NB_CONVW) * 256 + t;
        int e = id / HIDDEN, n = id - e * HIDDEN;
        float acc = b1[n];
#pragma unroll
        for (int k = 0; k < META; k++)
            acc += ed_table[e * META + k] * W1[(size_t)(2 * HIDDEN + k) * HIDDEN + n];
        Epp[id] = f2bf(acc);
    }
}

// ---- AW[4096][1536] = Mb @ Wt^T  (m97 structure: 128x128 tile, global_load_lds) ----
__global__ __launch_bounds__(256) void k_gemm(const unsigned short* __restrict__ Mb,
                                              const unsigned short* __restrict__ Wt,
                                              unsigned short* __restrict__ AW) {
    __shared__ unsigned short As[128 * BK];   // [m][k], contiguous (global_load_lds layout)
    __shared__ unsigned short Bs[128 * BK];   // [n][k]
    const int m0 = blockIdx.x * 128;
    const int n0 = blockIdx.y * 128;
    const int t = threadIdx.x, w = t >> 6, lane = t & 63;
    const int wm = (w & 1) * 64, wn = (w >> 1) * 64;
    const int q = lane >> 4, r = lane & 15;
    const int lrow = lane >> 2, lcol = (lane & 3) * 8;      // staging coords
    const unsigned short* gA = Mb + (size_t)(m0 + w * 32 + lrow) * HIDDEN + lcol;
    const unsigned short* gB = Wt + (size_t)(n0 + w * 32 + lrow) * HIDDEN + lcol;
    unsigned short* lA = As + (w * 32) * BK;                // wave-uniform LDS base
    unsigned short* lB = Bs + (w * 32) * BK;
    f32x4 acc[4][4] = {};
    for (int k0 = 0; k0 < HIDDEN; k0 += BK) {
        GLOAD_LDS16(gA + k0, lA);
        GLOAD_LDS16(gA + k0 + 16 * HIDDEN, lA + 16 * BK);
        GLOAD_LDS16(gB + k0, lB);
        GLOAD_LDS16(gB + k0 + 16 * HIDDEN, lB + 16 * BK);
        __syncthreads();
        bf16x8 af[4], bfr[4];
#pragma unroll
        for (int i = 0; i < 4; i++) af[i]  = *(const bf16x8*)&As[(wm + i * 16 + r) * BK + q * 8];
#pragma unroll
        for (int j = 0; j < 4; j++) bfr[j] = *(const bf16x8*)&Bs[(wn + j * 16 + r) * BK + q * 8];
#pragma unroll
        for (int i = 0; i < 4; i++)
#pragma unroll
            for (int j = 0; j < 4; j++)
                acc[i][j] = __builtin_amdgcn_mfma_f32_16x16x32_bf16(af[i], bfr[j], acc[i][j], 0, 0, 0);
        __syncthreads();
    }
    // C/D layout: col = lane&15, row = (lane>>4)*4 + reg
    const int colb = n0 + wn + (lane & 15);
    const int rowb = m0 + wm + (lane >> 4) * 4;
#pragma unroll
    for (int i = 0; i < 4; i++)
#pragma unroll
        for (int j = 0; j < 4; j++) {
            unsigned short* dst = AW + (size_t)(rowb + i * 16) * N_OUT + colb + j * 16;
#pragma unroll
            for (int reg = 0; reg < 4; reg++)
                dst[(size_t)reg * N_OUT] = f2bf(acc[i][j][reg]);
        }
}

// ---- pair phase: 1 wave per pair ----
__global__ __launch_bounds__(256) void k_pair(const unsigned short* __restrict__ AW,
                                              const unsigned short* __restrict__ Epp,
                                              const float* __restrict__ W2,
                                              const float* __restrict__ b2,
                                              const int* __restrict__ pairs,
                                              const int* __restrict__ eds,
                                              float* __restrict__ out) {
    int p = blockIdx.x * 4 + (threadIdx.x >> 6);
    int lane = threadIdx.x & 63;
    int b = (p >= NPAIRS) ? 1 : 0;
    int i0 = pairs[p * 2 + 0];
    int i1 = pairs[p * 2 + 1];
    int ed = eds[p];
    const unsigned short* a1p = AW + (size_t)(b * NMENT + i0) * N_OUT;
    const unsigned short* a2p = AW + (size_t)(b * NMENT + i1) * N_OUT + HIDDEN;
    const unsigned short* ep = Epp + (size_t)ed * HIDDEN;
    float acc = 0.f;
#pragma unroll
    for (int j = 0; j < 3; j++) {
        int n = j * 256 + lane * 4;
        ushort4 u1 = *(const ushort4*)(a1p + n);
        ushort4 u2 = *(const ushort4*)(a2p + n);
        ushort4 e = *(const ushort4*)(ep + n);
        float4 wv = *(const float4*)(W2 + n);
        float h;
        h = bf2f(u1.x) + bf2f(u2.x) + bf2f(e.x); h = fmaxf(h, 0.f); acc += h * wv.x;
        h = bf2f(u1.y) + bf2f(u2.y) + bf2f(e.y); h = fmaxf(h, 0.f); acc += h * wv.y;
        h = bf2f(u1.z) + bf2f(u2.z) + bf2f(e.z); h = fmaxf(h, 0.f); acc += h * wv.z;
        h = bf2f(u1.w) + bf2f(u2.w) + bf2f(e.w); h = fmaxf(h, 0.f); acc += h * wv.w;
    }
#pragma unroll
    for (int off = 32; off > 0; off >>= 1) acc += __shfl_xor(acc, off, 64);
    if (lane == 0) out[p] = acc + b2[0];
}

extern "C" void kernel_launch(void* const* d_in, const int* in_sizes, int n_in,
                              void* d_out, int out_size, void* d_ws, size_t ws_size,
                              hipStream_t stream) {
    const float* mention  = (const float*)d_in[0];
    const int*   pairs    = (const int*)d_in[1];
    const int*   eds      = (const int*)d_in[2];
    const float* ed_table = (const float*)d_in[3];
    const float* W1       = (const float*)d_in[4];
    const float* b1       = (const float*)d_in[5];
    const float* W2       = (const float*)d_in[6];
    const float* b2       = (const float*)d_in[7];
    float* out = (float*)d_out;

    // workspace layout (~21.7 MB)
    char* ws = (char*)d_ws;
    unsigned short* Mb  = (unsigned short*)(ws);                       // 4096*768*2  = 6,291,456
    unsigned short* Wt  = (unsigned short*)(ws + 6291456);             // 1536*768*2  = 2,359,296
    unsigned short* AW  = (unsigned short*)(ws + 6291456 + 2359296);   // 4096*1536*2 = 12,582,912
    unsigned short* Epp = (unsigned short*)(ws + 6291456 + 2359296 + 12582912); // 300*768*2 = 460,800

    k_prep_all<<<dim3(NB_CONVM + NB_CONVW + NB_PREP), dim3(256), 0, stream>>>(
        mention, Mb, W1, Wt, ed_table, b1, Epp);
    k_gemm<<<dim3(M_PAD / 128, N_OUT / 128), dim3(256), 0, stream>>>(Mb, Wt, AW);
    k_pair<<<dim3(TOTAL_PAIRS / 4), dim3(256), 0, stream>>>(AW, Epp, W2, b2, pairs, eds, out);
}

// Round 3
// 132.602 us; speedup vs baseline: 1.1022x; 1.0151x over previous
//
#include <hip/hip_runtime.h>
#include <stdint.h>

#define HIDDEN 768
#define META 25
#define EDC 300
#define BB 2
#define NMENT 2000
#define NPAIRS 40000
#define M_ROWS (BB * NMENT)       // 4000
#define M_PAD 4096                // 32 * 128
#define N_OUT 1536
#define TOTAL_PAIRS (BB * NPAIRS) // 80000
#define BK 32

typedef __bf16 bf16x8 __attribute__((ext_vector_type(8)));
typedef float f32x4 __attribute__((ext_vector_type(4)));

static __device__ __forceinline__ float bf2f(unsigned short u) {
    union { unsigned int u; float f; } v; v.u = ((unsigned int)u) << 16; return v.f;
}
static __device__ __forceinline__ unsigned short f2bf(float f) {
    union { float f; unsigned int u; } v; v.f = f;
    unsigned int u = v.u;
    unsigned int r = (u + 0x7FFFu + ((u >> 16) & 1u)) >> 16;   // RNE
    return (unsigned short)r;
}

#define GLOAD_LDS16(g, l)                                                            \
    __builtin_amdgcn_global_load_lds((const __attribute__((address_space(1))) void*)(g), \
                                     (__attribute__((address_space(3))) void*)(l), 16, 0, 0)

// ---- fused prep: convM (3072 blocks) | convW (576 blocks) | ed prep (900 blocks) ----
#define NB_CONVM 3072              // (4096*768/4)/256
#define NB_CONVW 576               // 24*24
#define NB_PREP  900               // 300*768/256

__global__ __launch_bounds__(256) void k_prep_all(
        const float* __restrict__ M, unsigned short* __restrict__ Mb,
        const float* __restrict__ W1, unsigned short* __restrict__ Wt,
        const float* __restrict__ ed_table, const float* __restrict__ b1,
        unsigned short* __restrict__ Epp) {
    const int blk = blockIdx.x;
    const int t = threadIdx.x;
    if (blk < NB_CONVM) {
        // fp32 mentions -> bf16, padded to 4096 rows (zero fill)
        int idx = (blk * 256 + t) * 4;
        int row = idx / HIDDEN;
        ushort4 o;
        if (row < M_ROWS) {
            const float4 v = *(const float4*)(M + idx);
            o.x = f2bf(v.x); o.y = f2bf(v.y); o.z = f2bf(v.z); o.w = f2bf(v.w);
        } else {
            o.x = 0; o.y = 0; o.z = 0; o.w = 0;
        }
        *(ushort4*)(Mb + idx) = o;
    } else if (blk < NB_CONVM + NB_CONVW) {
        // W1 combined view -> Wt[n][k] bf16 (transpose via LDS tile)
        __shared__ float tile[32][68];
        int id = blk - NB_CONVM;
        int nt = id % 24, kt = id / 24;
        int n0 = nt * 64, k0 = kt * 32;
        int tk = t >> 4, tn = (t & 15) * 4;
        int srcRowOff = (n0 < HIDDEN) ? 0 : HIDDEN;
        int srcColBase = (n0 < HIDDEN) ? n0 : (n0 - HIDDEN);
        {
            const float4 v0 = *(const float4*)(W1 + (size_t)(k0 + tk + srcRowOff) * HIDDEN + srcColBase + tn);
            tile[tk][tn] = v0.x; tile[tk][tn + 1] = v0.y; tile[tk][tn + 2] = v0.z; tile[tk][tn + 3] = v0.w;
            const float4 v1 = *(const float4*)(W1 + (size_t)(k0 + tk + 16 + srcRowOff) * HIDDEN + srcColBase + tn);
            tile[tk + 16][tn] = v1.x; tile[tk + 16][tn + 1] = v1.y; tile[tk + 16][tn + 2] = v1.z; tile[tk + 16][tn + 3] = v1.w;
        }
        __syncthreads();
        int wn = t >> 2, wk = (t & 3) * 8;
        unsigned int p0 = (unsigned int)f2bf(tile[wk + 0][wn]) | ((unsigned int)f2bf(tile[wk + 1][wn]) << 16);
        unsigned int p1 = (unsigned int)f2bf(tile[wk + 2][wn]) | ((unsigned int)f2bf(tile[wk + 3][wn]) << 16);
        unsigned int p2 = (unsigned int)f2bf(tile[wk + 4][wn]) | ((unsigned int)f2bf(tile[wk + 5][wn]) << 16);
        unsigned int p3 = (unsigned int)f2bf(tile[wk + 6][wn]) | ((unsigned int)f2bf(tile[wk + 7][wn]) << 16);
        uint4 pk; pk.x = p0; pk.y = p1; pk.z = p2; pk.w = p3;
        *(uint4*)(Wt + (size_t)(n0 + wn) * HIDDEN + k0 + wk) = pk;
    } else {
        // E''[e][n] = ed_table[e] @ W1[1536:1561] + b1  -> bf16
        int id = (blk - NB_CONVM - NB_CONVW) * 256 + t;
        int e = id / HIDDEN, n = id - e * HIDDEN;
        float acc = b1[n];
#pragma unroll
        for (int k = 0; k < META; k++)
            acc += ed_table[e * META + k] * W1[(size_t)(2 * HIDDEN + k) * HIDDEN + n];
        Epp[id] = f2bf(acc);
    }
}

// ---- AW[4096][1536] = Mb @ Wt^T ----
// 128x64 block tile (M x N), BK=32 -> grid 32x24 = 768 blocks = 3/CU exact.
// 4 waves in 2x2; each wave computes 64x32 (4x2 MFMA tiles), acc = 32 VGPR.
__global__ __launch_bounds__(256) void k_gemm(const unsigned short* __restrict__ Mb,
                                              const unsigned short* __restrict__ Wt,
                                              unsigned short* __restrict__ AW) {
    __shared__ unsigned short As[128 * BK];   // [m][k] contiguous (global_load_lds layout)
    __shared__ unsigned short Bs[64 * BK];    // [n][k]
    const int m0 = blockIdx.x * 128;
    const int n0 = blockIdx.y * 64;
    const int t = threadIdx.x, w = t >> 6, lane = t & 63;
    const int wm = (w & 1) * 64, wn = (w >> 1) * 32;
    const int q = lane >> 4, r = lane & 15;
    const int lrow = lane >> 2, lcol = (lane & 3) * 8;      // staging coords (16 rows x 32 cols per load)
    const unsigned short* gA = Mb + (size_t)(m0 + w * 32 + lrow) * HIDDEN + lcol;
    const unsigned short* gB = Wt + (size_t)(n0 + w * 16 + lrow) * HIDDEN + lcol;
    unsigned short* lA = As + (w * 32) * BK;                // wave-uniform LDS base
    unsigned short* lB = Bs + (w * 16) * BK;
    f32x4 acc[4][2] = {};
    for (int k0 = 0; k0 < HIDDEN; k0 += BK) {
        GLOAD_LDS16(gA + k0, lA);
        GLOAD_LDS16(gA + k0 + 16 * HIDDEN, lA + 16 * BK);
        GLOAD_LDS16(gB + k0, lB);
        __syncthreads();
        bf16x8 af[4], bfr[2];
#pragma unroll
        for (int i = 0; i < 4; i++) af[i]  = *(const bf16x8*)&As[(wm + i * 16 + r) * BK + q * 8];
#pragma unroll
        for (int j = 0; j < 2; j++) bfr[j] = *(const bf16x8*)&Bs[(wn + j * 16 + r) * BK + q * 8];
#pragma unroll
        for (int i = 0; i < 4; i++)
#pragma unroll
            for (int j = 0; j < 2; j++)
                acc[i][j] = __builtin_amdgcn_mfma_f32_16x16x32_bf16(af[i], bfr[j], acc[i][j], 0, 0, 0);
        __syncthreads();
    }
    // C/D layout: col = lane&15, row = (lane>>4)*4 + reg
    const int colb = n0 + wn + (lane & 15);
    const int rowb = m0 + wm + (lane >> 4) * 4;
#pragma unroll
    for (int i = 0; i < 4; i++)
#pragma unroll
        for (int j = 0; j < 2; j++) {
            unsigned short* dst = AW + (size_t)(rowb + i * 16) * N_OUT + colb + j * 16;
#pragma unroll
            for (int reg = 0; reg < 4; reg++)
                dst[(size_t)reg * N_OUT] = f2bf(acc[i][j][reg]);
        }
}

// ---- pair phase: 1 wave per pair ----
__global__ __launch_bounds__(256) void k_pair(const unsigned short* __restrict__ AW,
                                              const unsigned short* __restrict__ Epp,
                                              const float* __restrict__ W2,
                                              const float* __restrict__ b2,
                                              const int* __restrict__ pairs,
                                              const int* __restrict__ eds,
                                              float* __restrict__ out) {
    int p = blockIdx.x * 4 + (threadIdx.x >> 6);
    int lane = threadIdx.x & 63;
    int b = (p >= NPAIRS) ? 1 : 0;
    int i0 = pairs[p * 2 + 0];
    int i1 = pairs[p * 2 + 1];
    int ed = eds[p];
    const unsigned short* a1p = AW + (size_t)(b * NMENT + i0) * N_OUT;
    const unsigned short* a2p = AW + (size_t)(b * NMENT + i1) * N_OUT + HIDDEN;
    const unsigned short* ep = Epp + (size_t)ed * HIDDEN;
    float acc = 0.f;
#pragma unroll
    for (int j = 0; j < 3; j++) {
        int n = j * 256 + lane * 4;
        ushort4 u1 = *(const ushort4*)(a1p + n);
        ushort4 u2 = *(const ushort4*)(a2p + n);
        ushort4 e = *(const ushort4*)(ep + n);
        float4 wv = *(const float4*)(W2 + n);
        float h;
        h = bf2f(u1.x) + bf2f(u2.x) + bf2f(e.x); h = fmaxf(h, 0.f); acc += h * wv.x;
        h = bf2f(u1.y) + bf2f(u2.y) + bf2f(e.y); h = fmaxf(h, 0.f); acc += h * wv.y;
        h = bf2f(u1.z) + bf2f(u2.z) + bf2f(e.z); h = fmaxf(h, 0.f); acc += h * wv.z;
        h = bf2f(u1.w) + bf2f(u2.w) + bf2f(e.w); h = fmaxf(h, 0.f); acc += h * wv.w;
    }
#pragma unroll
    for (int off = 32; off > 0; off >>= 1) acc += __shfl_xor(acc, off, 64);
    if (lane == 0) out[p] = acc + b2[0];
}

extern "C" void kernel_launch(void* const* d_in, const int* in_sizes, int n_in,
                              void* d_out, int out_size, void* d_ws, size_t ws_size,
                              hipStream_t stream) {
    const float* mention  = (const float*)d_in[0];
    const int*   pairs    = (const int*)d_in[1];
    const int*   eds      = (const int*)d_in[2];
    const float* ed_table = (const float*)d_in[3];
    const float* W1       = (const float*)d_in[4];
    const float* b1       = (const float*)d_in[5];
    const float* W2       = (const float*)d_in[6];
    const float* b2       = (const float*)d_in[7];
    float* out = (float*)d_out;

    // workspace layout (~21.7 MB)
    char* ws = (char*)d_ws;
    unsigned short* Mb  = (unsigned short*)(ws);                       // 4096*768*2  = 6,291,456
    unsigned short* Wt  = (unsigned short*)(ws + 6291456);             // 1536*768*2  = 2,359,296
    unsigned short* AW  = (unsigned short*)(ws + 6291456 + 2359296);   // 4096*1536*2 = 12,582,912
    unsigned short* Epp = (unsigned short*)(ws + 6291456 + 2359296 + 12582912); // 300*768*2 = 460,800

    k_prep_all<<<dim3(NB_CONVM + NB_CONVW + NB_PREP), dim3(256), 0, stream>>>(
        mention, Mb, W1, Wt, ed_table, b1, Epp);
    k_gemm<<<dim3(M_PAD / 128, N_OUT / 64), dim3(256), 0, stream>>>(Mb, Wt, AW);
    k_pair<<<dim3(TOTAL_PAIRS / 4), dim3(256), 0, stream>>>(AW, Epp, W2, b2, pairs, eds, out);
}

// Round 4
// 122.906 us; speedup vs baseline: 1.1891x; 1.0789x over previous
//
#include <hip/hip_runtime.h>
#include <stdint.h>

#define HIDDEN 768
#define META 25
#define EDC 300
#define BB 2
#define NMENT 2000
#define NPAIRS 40000
#define M_ROWS (BB * NMENT)       // 4000
#define M_PAD 4096                // 32 * 128
#define N_OUT 1536
#define TOTAL_PAIRS (BB * NPAIRS) // 80000
#define BK 32

typedef __bf16 bf16x8 __attribute__((ext_vector_type(8)));
typedef float f32x4 __attribute__((ext_vector_type(4)));

static __device__ __forceinline__ float bf2f(unsigned short u) {
    union { unsigned int u; float f; } v; v.u = ((unsigned int)u) << 16; return v.f;
}
// unpack a uint holding 2 bf16 (lo, hi) to 2 floats
static __device__ __forceinline__ float2 bf2x(unsigned int u) {
    union { unsigned int x; float f; } lo, hi;
    lo.x = u << 16; hi.x = u & 0xffff0000u;
    float2 r; r.x = lo.f; r.y = hi.f; return r;
}
static __device__ __forceinline__ unsigned short f2bf(float f) {
    union { float f; unsigned int u; } v; v.f = f;
    unsigned int u = v.u;
    unsigned int r = (u + 0x7FFFu + ((u >> 16) & 1u)) >> 16;   // RNE
    return (unsigned short)r;
}

#define GLOAD_LDS16(g, l)                                                            \
    __builtin_amdgcn_global_load_lds((const __attribute__((address_space(1))) void*)(g), \
                                     (__attribute__((address_space(3))) void*)(l), 16, 0, 0)

// ---- fused prep: convM | convW | ed prep | W2->bf16 ----
#define NB_CONVM 3072              // (4096*768/4)/256
#define NB_CONVW 576               // 24*24
#define NB_PREP  900               // 300*768/256
#define NB_W2    3                 // 768/256

__global__ __launch_bounds__(256) void k_prep_all(
        const float* __restrict__ M, unsigned short* __restrict__ Mb,
        const float* __restrict__ W1, unsigned short* __restrict__ Wt,
        const float* __restrict__ ed_table, const float* __restrict__ b1,
        unsigned short* __restrict__ Epp,
        const float* __restrict__ W2, unsigned short* __restrict__ W2b) {
    const int blk = blockIdx.x;
    const int t = threadIdx.x;
    if (blk < NB_CONVM) {
        // fp32 mentions -> bf16, padded to 4096 rows (zero fill)
        int idx = (blk * 256 + t) * 4;
        int row = idx / HIDDEN;
        ushort4 o;
        if (row < M_ROWS) {
            const float4 v = *(const float4*)(M + idx);
            o.x = f2bf(v.x); o.y = f2bf(v.y); o.z = f2bf(v.z); o.w = f2bf(v.w);
        } else {
            o.x = 0; o.y = 0; o.z = 0; o.w = 0;
        }
        *(ushort4*)(Mb + idx) = o;
    } else if (blk < NB_CONVM + NB_CONVW) {
        // W1 combined view -> Wt[n][k] bf16 (transpose via LDS tile)
        __shared__ float tile[32][68];
        int id = blk - NB_CONVM;
        int nt = id % 24, kt = id / 24;
        int n0 = nt * 64, k0 = kt * 32;
        int tk = t >> 4, tn = (t & 15) * 4;
        int srcRowOff = (n0 < HIDDEN) ? 0 : HIDDEN;
        int srcColBase = (n0 < HIDDEN) ? n0 : (n0 - HIDDEN);
        {
            const float4 v0 = *(const float4*)(W1 + (size_t)(k0 + tk + srcRowOff) * HIDDEN + srcColBase + tn);
            tile[tk][tn] = v0.x; tile[tk][tn + 1] = v0.y; tile[tk][tn + 2] = v0.z; tile[tk][tn + 3] = v0.w;
            const float4 v1 = *(const float4*)(W1 + (size_t)(k0 + tk + 16 + srcRowOff) * HIDDEN + srcColBase + tn);
            tile[tk + 16][tn] = v1.x; tile[tk + 16][tn + 1] = v1.y; tile[tk + 16][tn + 2] = v1.z; tile[tk + 16][tn + 3] = v1.w;
        }
        __syncthreads();
        int wn = t >> 2, wk = (t & 3) * 8;
        unsigned int p0 = (unsigned int)f2bf(tile[wk + 0][wn]) | ((unsigned int)f2bf(tile[wk + 1][wn]) << 16);
        unsigned int p1 = (unsigned int)f2bf(tile[wk + 2][wn]) | ((unsigned int)f2bf(tile[wk + 3][wn]) << 16);
        unsigned int p2 = (unsigned int)f2bf(tile[wk + 4][wn]) | ((unsigned int)f2bf(tile[wk + 5][wn]) << 16);
        unsigned int p3 = (unsigned int)f2bf(tile[wk + 6][wn]) | ((unsigned int)f2bf(tile[wk + 7][wn]) << 16);
        uint4 pk; pk.x = p0; pk.y = p1; pk.z = p2; pk.w = p3;
        *(uint4*)(Wt + (size_t)(n0 + wn) * HIDDEN + k0 + wk) = pk;
    } else if (blk < NB_CONVM + NB_CONVW + NB_PREP) {
        // E''[e][n] = ed_table[e] @ W1[1536:1561] + b1  -> bf16
        int id = (blk - NB_CONVM - NB_CONVW) * 256 + t;
        int e = id / HIDDEN, n = id - e * HIDDEN;
        float acc = b1[n];
#pragma unroll
        for (int k = 0; k < META; k++)
            acc += ed_table[e * META + k] * W1[(size_t)(2 * HIDDEN + k) * HIDDEN + n];
        Epp[id] = f2bf(acc);
    } else {
        int id = (blk - NB_CONVM - NB_CONVW - NB_PREP) * 256 + t;
        if (id < HIDDEN) W2b[id] = f2bf(W2[id]);
    }
}

// ---- AW[4096][1536] = Mb @ Wt^T ----
// 128x64 block tile (M x N), BK=32 -> grid 32x24 = 768 blocks = 3/CU exact.
__global__ __launch_bounds__(256) void k_gemm(const unsigned short* __restrict__ Mb,
                                              const unsigned short* __restrict__ Wt,
                                              unsigned short* __restrict__ AW) {
    __shared__ unsigned short As[128 * BK];   // [m][k] contiguous (global_load_lds layout)
    __shared__ unsigned short Bs[64 * BK];    // [n][k]
    const int m0 = blockIdx.x * 128;
    const int n0 = blockIdx.y * 64;
    const int t = threadIdx.x, w = t >> 6, lane = t & 63;
    const int wm = (w & 1) * 64, wn = (w >> 1) * 32;
    const int q = lane >> 4, r = lane & 15;
    const int lrow = lane >> 2, lcol = (lane & 3) * 8;      // staging coords (16 rows x 32 cols per load)
    const unsigned short* gA = Mb + (size_t)(m0 + w * 32 + lrow) * HIDDEN + lcol;
    const unsigned short* gB = Wt + (size_t)(n0 + w * 16 + lrow) * HIDDEN + lcol;
    unsigned short* lA = As + (w * 32) * BK;                // wave-uniform LDS base
    unsigned short* lB = Bs + (w * 16) * BK;
    f32x4 acc[4][2] = {};
    for (int k0 = 0; k0 < HIDDEN; k0 += BK) {
        GLOAD_LDS16(gA + k0, lA);
        GLOAD_LDS16(gA + k0 + 16 * HIDDEN, lA + 16 * BK);
        GLOAD_LDS16(gB + k0, lB);
        __syncthreads();
        bf16x8 af[4], bfr[2];
#pragma unroll
        for (int i = 0; i < 4; i++) af[i]  = *(const bf16x8*)&As[(wm + i * 16 + r) * BK + q * 8];
#pragma unroll
        for (int j = 0; j < 2; j++) bfr[j] = *(const bf16x8*)&Bs[(wn + j * 16 + r) * BK + q * 8];
#pragma unroll
        for (int i = 0; i < 4; i++)
#pragma unroll
            for (int j = 0; j < 2; j++)
                acc[i][j] = __builtin_amdgcn_mfma_f32_16x16x32_bf16(af[i], bfr[j], acc[i][j], 0, 0, 0);
        __syncthreads();
    }
    // C/D layout: col = lane&15, row = (lane>>4)*4 + reg
    const int colb = n0 + wn + (lane & 15);
    const int rowb = m0 + wm + (lane >> 4) * 4;
#pragma unroll
    for (int i = 0; i < 4; i++)
#pragma unroll
        for (int j = 0; j < 2; j++) {
            unsigned short* dst = AW + (size_t)(rowb + i * 16) * N_OUT + colb + j * 16;
#pragma unroll
            for (int reg = 0; reg < 4; reg++)
                dst[(size_t)reg * N_OUT] = f2bf(acc[i][j][reg]);
        }
}

// ---- pair phase: 2 pairs per wave, 16B loads, bf16 W2 ----
// per pair each lane covers 12 elems: uint4 (8 bf16) at [lane*8, lane*8+8) and
// ushort4 (4 bf16) at [512 + lane*4, ...). All 16 row-loads issue before any wait.
__global__ __launch_bounds__(256) void k_pair(const unsigned short* __restrict__ AW,
                                              const unsigned short* __restrict__ Epp,
                                              const unsigned short* __restrict__ W2b,
                                              const float* __restrict__ b2,
                                              const int* __restrict__ pairs,
                                              const int* __restrict__ eds,
                                              float* __restrict__ out) {
    const int wid = blockIdx.x * 4 + (threadIdx.x >> 6);   // 0..39999
    const int lane = threadIdx.x & 63;
    const int pA = wid * 2, pB = pA + 1;
    const int bA = (pA >= NPAIRS) ? 1 : 0;
    const int bB = (pB >= NPAIRS) ? 1 : 0;
    const int n0 = lane * 8;            // chunk0 elem offset
    const int n1 = 512 + lane * 4;      // chunk1 elem offset

    const unsigned short* a1A = AW + (size_t)(bA * NMENT + pairs[pA * 2 + 0]) * N_OUT;
    const unsigned short* a2A = AW + (size_t)(bA * NMENT + pairs[pA * 2 + 1]) * N_OUT + HIDDEN;
    const unsigned short* epA = Epp + (size_t)eds[pA] * HIDDEN;
    const unsigned short* a1B = AW + (size_t)(bB * NMENT + pairs[pB * 2 + 0]) * N_OUT;
    const unsigned short* a2B = AW + (size_t)(bB * NMENT + pairs[pB * 2 + 1]) * N_OUT + HIDDEN;
    const unsigned short* epB = Epp + (size_t)eds[pB] * HIDDEN;

    // all loads up-front (max outstanding)
    uint4   wA0 = *(const uint4*)(W2b + n0);
    ushort4 wA1 = *(const ushort4*)(W2b + n1);
    uint4   x10 = *(const uint4*)(a1A + n0);
    uint4   x20 = *(const uint4*)(a2A + n0);
    uint4   xe0 = *(const uint4*)(epA + n0);
    ushort4 x11 = *(const ushort4*)(a1A + n1);
    ushort4 x21 = *(const ushort4*)(a2A + n1);
    ushort4 xe1 = *(const ushort4*)(epA + n1);
    uint4   y10 = *(const uint4*)(a1B + n0);
    uint4   y20 = *(const uint4*)(a2B + n0);
    uint4   ye0 = *(const uint4*)(epB + n0);
    ushort4 y11 = *(const ushort4*)(a1B + n1);
    ushort4 y21 = *(const ushort4*)(a2B + n1);
    ushort4 ye1 = *(const ushort4*)(epB + n1);

    float accA = 0.f, accB = 0.f;
#define ACC2(acc, ua, ub, ue, uw)                                              \
    {                                                                          \
        float2 fa = bf2x(ua), fb = bf2x(ub), fe = bf2x(ue), fw = bf2x(uw);     \
        float h0 = fmaxf(fa.x + fb.x + fe.x, 0.f);                             \
        float h1 = fmaxf(fa.y + fb.y + fe.y, 0.f);                             \
        acc += h0 * fw.x + h1 * fw.y;                                          \
    }
#define ACC1(acc, sa, sb, se, sw)                                              \
    {                                                                          \
        float h = fmaxf(bf2f(sa) + bf2f(sb) + bf2f(se), 0.f);                  \
        acc += h * bf2f(sw);                                                   \
    }
    ACC2(accA, x10.x, x20.x, xe0.x, wA0.x); ACC2(accA, x10.y, x20.y, xe0.y, wA0.y);
    ACC2(accA, x10.z, x20.z, xe0.z, wA0.z); ACC2(accA, x10.w, x20.w, xe0.w, wA0.w);
    ACC1(accA, x11.x, x21.x, xe1.x, wA1.x); ACC1(accA, x11.y, x21.y, xe1.y, wA1.y);
    ACC1(accA, x11.z, x21.z, xe1.z, wA1.z); ACC1(accA, x11.w, x21.w, xe1.w, wA1.w);
    ACC2(accB, y10.x, y20.x, ye0.x, wA0.x); ACC2(accB, y10.y, y20.y, ye0.y, wA0.y);
    ACC2(accB, y10.z, y20.z, ye0.z, wA0.z); ACC2(accB, y10.w, y20.w, ye0.w, wA0.w);
    ACC1(accB, y11.x, y21.x, ye1.x, wA1.x); ACC1(accB, y11.y, y21.y, ye1.y, wA1.y);
    ACC1(accB, y11.z, y21.z, ye1.z, wA1.z); ACC1(accB, y11.w, y21.w, ye1.w, wA1.w);
#undef ACC2
#undef ACC1
#pragma unroll
    for (int off = 32; off > 0; off >>= 1) {
        accA += __shfl_xor(accA, off, 64);
        accB += __shfl_xor(accB, off, 64);
    }
    if (lane == 0) {
        float bias = b2[0];
        out[pA] = accA + bias;
        out[pB] = accB + bias;
    }
}

extern "C" void kernel_launch(void* const* d_in, const int* in_sizes, int n_in,
                              void* d_out, int out_size, void* d_ws, size_t ws_size,
                              hipStream_t stream) {
    const float* mention  = (const float*)d_in[0];
    const int*   pairs    = (const int*)d_in[1];
    const int*   eds      = (const int*)d_in[2];
    const float* ed_table = (const float*)d_in[3];
    const float* W1       = (const float*)d_in[4];
    const float* b1       = (const float*)d_in[5];
    const float* W2       = (const float*)d_in[6];
    const float* b2       = (const float*)d_in[7];
    float* out = (float*)d_out;

    // workspace layout (~21.7 MB)
    char* ws = (char*)d_ws;
    unsigned short* Mb  = (unsigned short*)(ws);                       // 4096*768*2  = 6,291,456
    unsigned short* Wt  = (unsigned short*)(ws + 6291456);             // 1536*768*2  = 2,359,296
    unsigned short* AW  = (unsigned short*)(ws + 6291456 + 2359296);   // 4096*1536*2 = 12,582,912
    unsigned short* Epp = (unsigned short*)(ws + 6291456 + 2359296 + 12582912); // 300*768*2 = 460,800
    unsigned short* W2b = (unsigned short*)(ws + 6291456 + 2359296 + 12582912 + 460800); // 768*2

    k_prep_all<<<dim3(NB_CONVM + NB_CONVW + NB_PREP + NB_W2), dim3(256), 0, stream>>>(
        mention, Mb, W1, Wt, ed_table, b1, Epp, W2, W2b);
    k_gemm<<<dim3(M_PAD / 128, N_OUT / 64), dim3(256), 0, stream>>>(Mb, Wt, AW);
    k_pair<<<dim3(TOTAL_PAIRS / 8), dim3(256), 0, stream>>>(AW, Epp, W2b, b2, pairs, eds, out);
}

// Round 5
// 121.660 us; speedup vs baseline: 1.2013x; 1.0102x over previous
//
#include <hip/hip_runtime.h>
#include <stdint.h>

#define HIDDEN 768
#define META 25
#define EDC 300
#define BB 2
#define NMENT 2000
#define NPAIRS 40000
#define M_ROWS (BB * NMENT)       // 4000
#define M_PAD 4096                // 32 * 128
#define N_OUT 1536
#define TOTAL_PAIRS (BB * NPAIRS) // 80000
#define BK 32

typedef __bf16 bf16x8 __attribute__((ext_vector_type(8)));
typedef float f32x4 __attribute__((ext_vector_type(4)));

static __device__ __forceinline__ float bf2f(unsigned short u) {
    union { unsigned int u; float f; } v; v.u = ((unsigned int)u) << 16; return v.f;
}
static __device__ __forceinline__ float2 bf2x(unsigned int u) {
    union { unsigned int x; float f; } lo, hi;
    lo.x = u << 16; hi.x = u & 0xffff0000u;
    float2 r; r.x = lo.f; r.y = hi.f; return r;
}
static __device__ __forceinline__ unsigned short f2bf(float f) {
    union { float f; unsigned int u; } v; v.f = f;
    unsigned int u = v.u;
    unsigned int r = (u + 0x7FFFu + ((u >> 16) & 1u)) >> 16;   // RNE
    return (unsigned short)r;
}

#define GLOAD_LDS16(g, l)                                                            \
    __builtin_amdgcn_global_load_lds((const __attribute__((address_space(1))) void*)(g), \
                                     (__attribute__((address_space(3))) void*)(l), 16, 0, 0)

// ---- fused prep: convM | convW | ed prep | W2->bf16 ----
#define NB_CONVM 3072              // (4096*768/4)/256
#define NB_CONVW 576               // 24*24
#define NB_PREP  900               // 300*768/256
#define NB_W2    3                 // 768/256

__global__ __launch_bounds__(256) void k_prep_all(
        const float* __restrict__ M, unsigned short* __restrict__ Mb,
        const float* __restrict__ W1, unsigned short* __restrict__ Wt,
        const float* __restrict__ ed_table, const float* __restrict__ b1,
        unsigned short* __restrict__ Epp,
        const float* __restrict__ W2, unsigned short* __restrict__ W2b) {
    const int blk = blockIdx.x;
    const int t = threadIdx.x;
    if (blk < NB_CONVM) {
        int idx = (blk * 256 + t) * 4;
        int row = idx / HIDDEN;
        ushort4 o;
        if (row < M_ROWS) {
            const float4 v = *(const float4*)(M + idx);
            o.x = f2bf(v.x); o.y = f2bf(v.y); o.z = f2bf(v.z); o.w = f2bf(v.w);
        } else {
            o.x = 0; o.y = 0; o.z = 0; o.w = 0;
        }
        *(ushort4*)(Mb + idx) = o;
    } else if (blk < NB_CONVM + NB_CONVW) {
        __shared__ float tile[32][68];
        int id = blk - NB_CONVM;
        int nt = id % 24, kt = id / 24;
        int n0 = nt * 64, k0 = kt * 32;
        int tk = t >> 4, tn = (t & 15) * 4;
        int srcRowOff = (n0 < HIDDEN) ? 0 : HIDDEN;
        int srcColBase = (n0 < HIDDEN) ? n0 : (n0 - HIDDEN);
        {
            const float4 v0 = *(const float4*)(W1 + (size_t)(k0 + tk + srcRowOff) * HIDDEN + srcColBase + tn);
            tile[tk][tn] = v0.x; tile[tk][tn + 1] = v0.y; tile[tk][tn + 2] = v0.z; tile[tk][tn + 3] = v0.w;
            const float4 v1 = *(const float4*)(W1 + (size_t)(k0 + tk + 16 + srcRowOff) * HIDDEN + srcColBase + tn);
            tile[tk + 16][tn] = v1.x; tile[tk + 16][tn + 1] = v1.y; tile[tk + 16][tn + 2] = v1.z; tile[tk + 16][tn + 3] = v1.w;
        }
        __syncthreads();
        int wn = t >> 2, wk = (t & 3) * 8;
        unsigned int p0 = (unsigned int)f2bf(tile[wk + 0][wn]) | ((unsigned int)f2bf(tile[wk + 1][wn]) << 16);
        unsigned int p1 = (unsigned int)f2bf(tile[wk + 2][wn]) | ((unsigned int)f2bf(tile[wk + 3][wn]) << 16);
        unsigned int p2 = (unsigned int)f2bf(tile[wk + 4][wn]) | ((unsigned int)f2bf(tile[wk + 5][wn]) << 16);
        unsigned int p3 = (unsigned int)f2bf(tile[wk + 6][wn]) | ((unsigned int)f2bf(tile[wk + 7][wn]) << 16);
        uint4 pk; pk.x = p0; pk.y = p1; pk.z = p2; pk.w = p3;
        *(uint4*)(Wt + (size_t)(n0 + wn) * HIDDEN + k0 + wk) = pk;
    } else if (blk < NB_CONVM + NB_CONVW + NB_PREP) {
        int id = (blk - NB_CONVM - NB_CONVW) * 256 + t;
        int e = id / HIDDEN, n = id - e * HIDDEN;
        float acc = b1[n];
#pragma unroll
        for (int k = 0; k < META; k++)
            acc += ed_table[e * META + k] * W1[(size_t)(2 * HIDDEN + k) * HIDDEN + n];
        Epp[id] = f2bf(acc);
    } else {
        int id = (blk - NB_CONVM - NB_CONVW - NB_PREP) * 256 + t;
        if (id < HIDDEN) W2b[id] = f2bf(W2[id]);
    }
}

// ---- AW[4096][1536] = Mb @ Wt^T ----
__global__ __launch_bounds__(256) void k_gemm(const unsigned short* __restrict__ Mb,
                                              const unsigned short* __restrict__ Wt,
                                              unsigned short* __restrict__ AW) {
    __shared__ unsigned short As[128 * BK];
    __shared__ unsigned short Bs[64 * BK];
    const int m0 = blockIdx.x * 128;
    const int n0 = blockIdx.y * 64;
    const int t = threadIdx.x, w = t >> 6, lane = t & 63;
    const int wm = (w & 1) * 64, wn = (w >> 1) * 32;
    const int q = lane >> 4, r = lane & 15;
    const int lrow = lane >> 2, lcol = (lane & 3) * 8;
    const unsigned short* gA = Mb + (size_t)(m0 + w * 32 + lrow) * HIDDEN + lcol;
    const unsigned short* gB = Wt + (size_t)(n0 + w * 16 + lrow) * HIDDEN + lcol;
    unsigned short* lA = As + (w * 32) * BK;
    unsigned short* lB = Bs + (w * 16) * BK;
    f32x4 acc[4][2] = {};
    for (int k0 = 0; k0 < HIDDEN; k0 += BK) {
        GLOAD_LDS16(gA + k0, lA);
        GLOAD_LDS16(gA + k0 + 16 * HIDDEN, lA + 16 * BK);
        GLOAD_LDS16(gB + k0, lB);
        __syncthreads();
        bf16x8 af[4], bfr[2];
#pragma unroll
        for (int i = 0; i < 4; i++) af[i]  = *(const bf16x8*)&As[(wm + i * 16 + r) * BK + q * 8];
#pragma unroll
        for (int j = 0; j < 2; j++) bfr[j] = *(const bf16x8*)&Bs[(wn + j * 16 + r) * BK + q * 8];
#pragma unroll
        for (int i = 0; i < 4; i++)
#pragma unroll
            for (int j = 0; j < 2; j++)
                acc[i][j] = __builtin_amdgcn_mfma_f32_16x16x32_bf16(af[i], bfr[j], acc[i][j], 0, 0, 0);
        __syncthreads();
    }
    const int colb = n0 + wn + (lane & 15);
    const int rowb = m0 + wm + (lane >> 4) * 4;
#pragma unroll
    for (int i = 0; i < 4; i++)
#pragma unroll
        for (int j = 0; j < 2; j++) {
            unsigned short* dst = AW + (size_t)(rowb + i * 16) * N_OUT + colb + j * 16;
#pragma unroll
            for (int reg = 0; reg < 4; reg++)
                dst[(size_t)reg * N_OUT] = f2bf(acc[i][j][reg]);
        }
}

// ---- pair phase: 4 pairs per wave ----
__global__ __launch_bounds__(256) void k_pair(const unsigned short* __restrict__ AW,
                                              const unsigned short* __restrict__ Epp,
                                              const unsigned short* __restrict__ W2b,
                                              const float* __restrict__ b2,
                                              const int* __restrict__ pairs,
                                              const int* __restrict__ eds,
                                              float* __restrict__ out) {
    const int wid = blockIdx.x * 4 + (threadIdx.x >> 6);   // 0..19999
    const int lane = threadIdx.x & 63;
    const int p0 = wid * 4;
    const int b = (p0 >= NPAIRS) ? 1 : 0;                   // 40000 % 4 == 0: group shares batch
    const int n0 = lane * 8;
    const int n1 = 512 + lane * 4;

    const int4 pr01 = *(const int4*)(pairs + (size_t)p0 * 2);
    const int4 pr23 = *(const int4*)(pairs + (size_t)p0 * 2 + 4);
    const int4 ed4  = *(const int4*)(eds + p0);

    const size_t base = (size_t)(b * NMENT);
    const unsigned short* a1p0 = AW + (base + pr01.x) * N_OUT;
    const unsigned short* a2p0 = AW + (base + pr01.y) * N_OUT + HIDDEN;
    const unsigned short* ep0  = Epp + (size_t)ed4.x * HIDDEN;
    const unsigned short* a1p1 = AW + (base + pr01.z) * N_OUT;
    const unsigned short* a2p1 = AW + (base + pr01.w) * N_OUT + HIDDEN;
    const unsigned short* ep1  = Epp + (size_t)ed4.y * HIDDEN;
    const unsigned short* a1p2 = AW + (base + pr23.x) * N_OUT;
    const unsigned short* a2p2 = AW + (base + pr23.y) * N_OUT + HIDDEN;
    const unsigned short* ep2  = Epp + (size_t)ed4.z * HIDDEN;
    const unsigned short* a1p3 = AW + (base + pr23.z) * N_OUT;
    const unsigned short* a2p3 = AW + (base + pr23.w) * N_OUT + HIDDEN;
    const unsigned short* ep3  = Epp + (size_t)ed4.w * HIDDEN;

    uint4   w0 = *(const uint4*)(W2b + n0);
    ushort4 w1 = *(const ushort4*)(W2b + n1);
    uint4   x10 = *(const uint4*)(a1p0 + n0), x20 = *(const uint4*)(a2p0 + n0), xe0 = *(const uint4*)(ep0 + n0);
    uint4   y10 = *(const uint4*)(a1p1 + n0), y20 = *(const uint4*)(a2p1 + n0), ye0 = *(const uint4*)(ep1 + n0);
    uint4   z10 = *(const uint4*)(a1p2 + n0), z20 = *(const uint4*)(a2p2 + n0), ze0 = *(const uint4*)(ep2 + n0);
    uint4   v10 = *(const uint4*)(a1p3 + n0), v20 = *(const uint4*)(a2p3 + n0), ve0 = *(const uint4*)(ep3 + n0);
    ushort4 x11 = *(const ushort4*)(a1p0 + n1), x21 = *(const ushort4*)(a2p0 + n1), xe1 = *(const ushort4*)(ep0 + n1);
    ushort4 y11 = *(const ushort4*)(a1p1 + n1), y21 = *(const ushort4*)(a2p1 + n1), ye1 = *(const ushort4*)(ep1 + n1);
    ushort4 z11 = *(const ushort4*)(a1p2 + n1), z21 = *(const ushort4*)(a2p2 + n1), ze1 = *(const ushort4*)(ep2 + n1);
    ushort4 v11 = *(const ushort4*)(a1p3 + n1), v21 = *(const ushort4*)(a2p3 + n1), ve1 = *(const ushort4*)(ep3 + n1);

    float acc0 = 0.f, acc1 = 0.f, acc2 = 0.f, acc3 = 0.f;
#define ACC2(acc, ua, ub, ue, uw)                                              \
    {                                                                          \
        float2 fa = bf2x(ua), fb = bf2x(ub), fe = bf2x(ue), fw = bf2x(uw);     \
        float h0 = fmaxf(fa.x + fb.x + fe.x, 0.f);                             \
        float h1 = fmaxf(fa.y + fb.y + fe.y, 0.f);                             \
        acc += h0 * fw.x + h1 * fw.y;                                          \
    }
#define ACC1(acc, sa, sb, se, sw)                                              \
    {                                                                          \
        float h = fmaxf(bf2f(sa) + bf2f(sb) + bf2f(se), 0.f);                  \
        acc += h * bf2f(sw);                                                   \
    }
    ACC2(acc0, x10.x, x20.x, xe0.x, w0.x); ACC2(acc0, x10.y, x20.y, xe0.y, w0.y);
    ACC2(acc0, x10.z, x20.z, xe0.z, w0.z); ACC2(acc0, x10.w, x20.w, xe0.w, w0.w);
    ACC1(acc0, x11.x, x21.x, xe1.x, w1.x); ACC1(acc0, x11.y, x21.y, xe1.y, w1.y);
    ACC1(acc0, x11.z, x21.z, xe1.z, w1.z); ACC1(acc0, x11.w, x21.w, xe1.w, w1.w);
    ACC2(acc1, y10.x, y20.x, ye0.x, w0.x); ACC2(acc1, y10.y, y20.y, ye0.y, w0.y);
    ACC2(acc1, y10.z, y20.z, ye0.z, w0.z); ACC2(acc1, y10.w, y20.w, ye0.w, w0.w);
    ACC1(acc1, y11.x, y21.x, ye1.x, w1.x); ACC1(acc1, y11.y, y21.y, ye1.y, w1.y);
    ACC1(acc1, y11.z, y21.z, ye1.z, w1.z); ACC1(acc1, y11.w, y21.w, ye1.w, w1.w);
    ACC2(acc2, z10.x, z20.x, ze0.x, w0.x); ACC2(acc2, z10.y, z20.y, ze0.y, w0.y);
    ACC2(acc2, z10.z, z20.z, ze0.z, w0.z); ACC2(acc2, z10.w, z20.w, ze0.w, w0.w);
    ACC1(acc2, z11.x, z21.x, ze1.x, w1.x); ACC1(acc2, z11.y, z21.y, ze1.y, w1.y);
    ACC1(acc2, z11.z, z21.z, ze1.z, w1.z); ACC1(acc2, z11.w, z21.w, ze1.w, w1.w);
    ACC2(acc3, v10.x, v20.x, ve0.x, w0.x); ACC2(acc3, v10.y, v20.y, ve0.y, w0.y);
    ACC2(acc3, v10.z, v20.z, ve0.z, w0.z); ACC2(acc3, v10.w, v20.w, ve0.w, w0.w);
    ACC1(acc3, v11.x, v21.x, ve1.x, w1.x); ACC1(acc3, v11.y, v21.y, ve1.y, w1.y);
    ACC1(acc3, v11.z, v21.z, ve1.z, w1.z); ACC1(acc3, v11.w, v21.w, ve1.w, w1.w);
#undef ACC2
#undef ACC1
#pragma unroll
    for (int off = 32; off > 0; off >>= 1) {
        acc0 += __shfl_xor(acc0, off, 64);
        acc1 += __shfl_xor(acc1, off, 64);
        acc2 += __shfl_xor(acc2, off, 64);
        acc3 += __shfl_xor(acc3, off, 64);
    }
    if (lane == 0) {
        float bias = b2[0];
        float4 o; o.x = acc0 + bias; o.y = acc1 + bias; o.z = acc2 + bias; o.w = acc3 + bias;
        *(float4*)(out + p0) = o;
    }
}

extern "C" void kernel_launch(void* const* d_in, const int* in_sizes, int n_in,
                              void* d_out, int out_size, void* d_ws, size_t ws_size,
                              hipStream_t stream) {
    const float* mention  = (const float*)d_in[0];
    const int*   pairs    = (const int*)d_in[1];
    const int*   eds      = (const int*)d_in[2];
    const float* ed_table = (const float*)d_in[3];
    const float* W1       = (const float*)d_in[4];
    const float* b1       = (const float*)d_in[5];
    const float* W2       = (const float*)d_in[6];
    const float* b2       = (const float*)d_in[7];
    float* out = (float*)d_out;

    char* ws = (char*)d_ws;
    unsigned short* Mb  = (unsigned short*)(ws);                       // 4096*768*2  = 6,291,456
    unsigned short* Wt  = (unsigned short*)(ws + 6291456);             // 1536*768*2  = 2,359,296
    unsigned short* AW  = (unsigned short*)(ws + 6291456 + 2359296);   // 4096*1536*2 = 12,582,912
    unsigned short* Epp = (unsigned short*)(ws + 6291456 + 2359296 + 12582912); // 300*768*2 = 460,800
    unsigned short* W2b = (unsigned short*)(ws + 6291456 + 2359296 + 12582912 + 460800); // 768*2

    k_prep_all<<<dim3(NB_CONVM + NB_CONVW + NB_PREP + NB_W2), dim3(256), 0, stream>>>(
        mention, Mb, W1, Wt, ed_table, b1, Epp, W2, W2b);
    k_gemm<<<dim3(M_PAD / 128, N_OUT / 64), dim3(256), 0, stream>>>(Mb, Wt, AW);
    k_pair<<<dim3(TOTAL_PAIRS / 16), dim3(256), 0, stream>>>(AW, Epp, W2b, b2, pairs, eds, out);
}